// Round 10
// baseline (136.622 us; speedup 1.0000x reference)
//
#include <hip/hip_runtime.h>
#include <math.h>

#define BATCH 16
#define CIN 4
#define LEN 300000
#define KW 11
#define LC (LEN - KW + 1)   // 299990
#define LCP 300000          // padded ch row stride
#define LEAK 1e-4f
#define EPS_N 1e-12f

#define TPB 256
#define EPT 4
#define NBX 293              // ceil(LC / 1024): one float4 per thread, one shot
// grid = 293 x 16 = 4688 blocks per pass — maximize wave supply

// ws layout (no memset; written-before-read across kernel boundaries):
//   absP double[16*NBX]    @ 0       (37504 B)
//   sP   double[16*NBX*3]  @ 40960   (112512 B)
//   ch   float [16*LCP]    @ 196608  (19.2 MB)

__device__ inline float leaky(float v) { return v > 0.0f ? v : LEAK * v; }

__device__ inline void finalize_row(double e, double m1, double m2,
                                    float* __restrict__ out, int b)
{
    const double mean = m1 / e;
    const double var  = m2 / e - mean * mean;

    const double n   = (double)LC;
    const double nm1 = n - 1.0;
    const double S1p = 0.5 * n * nm1;
    const double S2p = nm1 * n * (2.0 * n - 1.0) / 6.0;
    const double S3p = S1p * S1p;
    const double S4p = S2p * (3.0 * n * n - 3.0 * n - 1.0) / 5.0;

    const double mu  = mean;
    const double mu2 = mu * mu;
    const double P3 = S3p - 3.0 * mu * S2p + 3.0 * mu2 * S1p - n * mu * mu2;
    const double P4 = S4p - 4.0 * mu * S3p + 6.0 * mu2 * S2p
                      - 4.0 * mu * mu2 * S1p + n * mu2 * mu2;

    const double sv = sqrt(var);
    out[b]         = (float)(P3 / (n * sv * sv * sv));
    out[BATCH + b] = (float)(P4 / (n * var * var) - 3.0);
}

// ---------------------------------------------------------------------------
// kernel 1: conv + leaky + |.| row partials.  One float4 of outputs per
// thread, zero held state, no atomics/fences — lean VGPR, max waves.
// ---------------------------------------------------------------------------
__global__ __launch_bounds__(256) void conv_stats(
    const float* __restrict__ data, const float* __restrict__ W,
    const float* __restrict__ bias, const int* __restrict__ aidx,
    float* __restrict__ ch, double* __restrict__ absP)
{
    const int b = blockIdx.y, j = blockIdx.x, tid = threadIdx.x;
    const int a = aidx[0];

    float w[CIN * KW];
#pragma unroll
    for (int k = 0; k < CIN * KW; ++k) w[k] = W[a * CIN * KW + k];
    const float sb = bias[a];

    const float* dbase = data + (size_t)b * (CIN * (size_t)LEN);
    float* chrow = ch + (size_t)b * LCP;
    const int o = j * (TPB * EPT) + tid * EPT;

    float aabs = 0.0f;

    if (o + EPT <= LC && o + 16 <= LEN) {
        float acc0 = sb, acc1 = sb, acc2 = sb, acc3 = sb;
#pragma unroll
        for (int c = 0; c < CIN; ++c) {
            const float* s = dbase + (size_t)c * LEN + o;
            const float4 v0 = *(const float4*)(s);
            const float4 v1 = *(const float4*)(s + 4);
            const float4 v2 = *(const float4*)(s + 8);
            const float4 v3 = *(const float4*)(s + 12);
            float x[16] = { v0.x, v0.y, v0.z, v0.w,  v1.x, v1.y, v1.z, v1.w,
                            v2.x, v2.y, v2.z, v2.w,  v3.x, v3.y, v3.z, v3.w };
#pragma unroll
            for (int k = 0; k < KW; ++k) {
                const float wv = w[c * KW + k];
                acc0 = fmaf(x[k],     wv, acc0);
                acc1 = fmaf(x[k + 1], wv, acc1);
                acc2 = fmaf(x[k + 2], wv, acc2);
                acc3 = fmaf(x[k + 3], wv, acc3);
            }
        }
        const float y0 = leaky(acc0), y1 = leaky(acc1);
        const float y2 = leaky(acc2), y3 = leaky(acc3);
        *(float4*)(chrow + o) = make_float4(y0, y1, y2, y3);
        aabs = (fabsf(y0) + fabsf(y1)) + (fabsf(y2) + fabsf(y3));
    } else {
        for (int l = o; l < min(o + EPT, LC); ++l) {
            float acc = sb;
#pragma unroll
            for (int c = 0; c < CIN; ++c)
#pragma unroll
                for (int k = 0; k < KW; ++k)
                    acc = fmaf(dbase[(size_t)c * LEN + l + k], w[c * KW + k], acc);
            const float y = leaky(acc);
            chrow[l] = y;
            aabs += fabsf(y);
        }
    }

#pragma unroll
    for (int off = 32; off; off >>= 1) aabs += __shfl_down(aabs, off);
    __shared__ float ra[4];
    if ((tid & 63) == 0) ra[tid >> 6] = aabs;
    __syncthreads();
    if (tid == 0)
        absP[b * NBX + j] = (double)((ra[0] + ra[1]) + (ra[2] + ra[3]));
}

// ---------------------------------------------------------------------------
// kernel 2: normalize + softmax-exp moments (no max shift: |c|<=1 after L1
// norm, exp(c) in [0.37, 2.72] — shift-invariance exact).  One float4/thread.
// ---------------------------------------------------------------------------
__global__ __launch_bounds__(256) void softmax_pass(
    const float* __restrict__ ch, const double* __restrict__ absP,
    float* __restrict__ chan_out, double* __restrict__ sP)
{
    const int b = blockIdx.y, j = blockIdx.x, tid = threadIdx.x;

    // redundant per-block row reduce of 293 partials (~1.2 KB, L2-served)
    __shared__ float sden;
    if (tid < 64) {
        double s = 0.0;
        for (int i = tid; i < NBX; i += 64) s += absP[b * NBX + i];
#pragma unroll
        for (int off = 32; off; off >>= 1) s += __shfl_down(s, off);
        if (tid == 0) sden = fmaxf((float)s, EPS_N);
    }
    __syncthreads();
    const float inv = 1.0f / sden;

    const float* src = ch + (size_t)b * LCP;
    float* dst = chan_out + (size_t)b * LC;   // elem base mod4 = (2b)&3
    const int o = j * (TPB * EPT) + tid * EPT;

    double te = 0.0, t1 = 0.0, t2 = 0.0;

    if (o + EPT <= LC) {
        const float4 v = *(const float4*)(src + o);
        const float c0 = v.x * inv, c1 = v.y * inv, c2 = v.z * inv, c3 = v.w * inv;
        if ((b & 1) == 0) {
            *(float4*)(dst + o) = make_float4(c0, c1, c2, c3);
        } else {                    // row base only 8B-aligned
            *(float2*)(dst + o)     = make_float2(c0, c1);
            *(float2*)(dst + o + 2) = make_float2(c2, c3);
        }
        const float e0 = expf(c0), e1 = expf(c1);
        const float e2 = expf(c2), e3 = expf(c3);
        const float se  = (e0 + e1) + (e2 + e3);
        const float su  = e1 + 2.0f * e2 + 3.0f * e3;
        const float suu = e1 + 4.0f * e2 + 9.0f * e3;
        const double od = (double)o;
        te = (double)se;
        t1 = od * (double)se + (double)su;
        t2 = od * od * (double)se + 2.0 * od * (double)su + (double)suu;
    } else {
        for (int l = o; l < LC; ++l) {
            const float c = src[l] * inv;
            dst[l] = c;
            const float e = expf(c);
            const double xd = (double)l;
            te += (double)e;
            t1 += (double)e * xd;
            t2 += (double)e * xd * xd;
        }
    }

#pragma unroll
    for (int off = 32; off; off >>= 1) {
        te += __shfl_down(te, off);
        t1 += __shfl_down(t1, off);
        t2 += __shfl_down(t2, off);
    }
    __shared__ double we[4], w1[4], w2[4];
    const int wv = tid >> 6;
    if ((tid & 63) == 0) { we[wv] = te; w1[wv] = t1; w2[wv] = t2; }
    __syncthreads();
    if (tid == 0) {
        double* p = sP + (size_t)(b * NBX + j) * 3;
        p[0] = (we[0] + we[1]) + (we[2] + we[3]);
        p[1] = (w1[0] + w1[1]) + (w1[2] + w1[3]);
        p[2] = (w2[0] + w2[1]) + (w2[2] + w2[3]);
    }
}

// ---------------------------------------------------------------------------
// kernel 3: finalize 16 rows
// ---------------------------------------------------------------------------
__global__ void finalize(const double* __restrict__ sP, float* __restrict__ out)
{
    const int b = blockIdx.x, t = threadIdx.x;
    double te = 0.0, t1 = 0.0, t2 = 0.0;
    for (int i = t; i < NBX; i += 64) {
        const double* p = sP + (size_t)(b * NBX + i) * 3;
        te += p[0]; t1 += p[1]; t2 += p[2];
    }
#pragma unroll
    for (int off = 32; off; off >>= 1) {
        te += __shfl_down(te, off);
        t1 += __shfl_down(t1, off);
        t2 += __shfl_down(t2, off);
    }
    if (t == 0) finalize_row(te, t1, t2, out, b);
}

extern "C" void kernel_launch(void* const* d_in, const int* in_sizes, int n_in,
                              void* d_out, int out_size, void* d_ws, size_t ws_size,
                              hipStream_t stream) {
    const float* data = (const float*)d_in[0];
    const float* W    = (const float*)d_in[1];
    const float* bias = (const float*)d_in[2];
    const int*   aidx = (const int*)d_in[3];
    float* out = (float*)d_out;

    char* ws = (char*)d_ws;
    double* absP = (double*)(ws + 0);
    double* sP   = (double*)(ws + 40960);
    float*  ch   = (float*) (ws + 196608);

    dim3 grid(NBX, BATCH);
    conv_stats<<<grid, dim3(TPB), 0, stream>>>(data, W, bias, aidx, ch, absP);
    softmax_pass<<<grid, dim3(TPB), 0, stream>>>(ch, absP, out + 2 * BATCH, sP);
    finalize<<<dim3(BATCH), dim3(64), 0, stream>>>(sP, out);
}

// Round 11
// 136.290 us; speedup vs baseline: 1.0024x; 1.0024x over previous
//
#include <hip/hip_runtime.h>
#include <math.h>
#include <stdint.h>

#define BATCH 16
#define CIN 4
#define LEN 300000
#define KW 11
#define LC (LEN - KW + 1)   // 299990
#define LCP 300000          // padded ch row stride
#define LEAK 1e-4f
#define EPS_N 1e-12f

#define TPB 256
#define EPT 4
#define TILE 1024            // outputs per block
#define NBX 293              // ceil(LC / TILE)
#define LROW 1056            // LDS row stride in floats (1040 staged + pad)

// ws layout (no memset; written-before-read across kernel boundaries):
//   absP double[16*NBX]    @ 0       (37504 B)
//   sP   double[16*NBX*3]  @ 40960   (112512 B)
//   ch   float [16*LCP]    @ 196608  (19.2 MB)

__device__ inline float leaky(float v) { return v > 0.0f ? v : LEAK * v; }

// async global->LDS DMA, 16B per lane; LDS dest = wave-uniform base + lane*16
__device__ __forceinline__ void g2l16(const float* g, float* l) {
    __builtin_amdgcn_global_load_lds(
        (const __attribute__((address_space(1))) uint32_t*)(uintptr_t)g,
        (__attribute__((address_space(3)))  uint32_t*)(uintptr_t)l,
        16, 0, 0);
}

__device__ inline void finalize_row(double e, double m1, double m2,
                                    float* __restrict__ out, int b)
{
    const double mean = m1 / e;
    const double var  = m2 / e - mean * mean;

    const double n   = (double)LC;
    const double nm1 = n - 1.0;
    const double S1p = 0.5 * n * nm1;
    const double S2p = nm1 * n * (2.0 * n - 1.0) / 6.0;
    const double S3p = S1p * S1p;
    const double S4p = S2p * (3.0 * n * n - 3.0 * n - 1.0) / 5.0;

    const double mu  = mean;
    const double mu2 = mu * mu;
    const double P3 = S3p - 3.0 * mu * S2p + 3.0 * mu2 * S1p - n * mu * mu2;
    const double P4 = S4p - 4.0 * mu * S3p + 6.0 * mu2 * S2p
                      - 4.0 * mu * mu2 * S1p + n * mu2 * mu2;

    const double sv = sqrt(var);
    out[b]         = (float)(P3 / (n * sv * sv * sv));
    out[BATCH + b] = (float)(P4 / (n * var * var) - 3.0);
}

// ---------------------------------------------------------------------------
// kernel 1: conv + leaky + |.| row partials — DMA-staged through LDS.
// wave w stages channel w: 5 global_load_lds_dwordx4 issued back-to-back
// (no VGPR round-trip, ~17KB in flight per block), one barrier drains,
// compute runs from LDS only.
// ---------------------------------------------------------------------------
__global__ __launch_bounds__(256) void conv_stats(
    const float* __restrict__ data, const float* __restrict__ W,
    const float* __restrict__ bias, const int* __restrict__ aidx,
    float* __restrict__ ch, double* __restrict__ absP)
{
    const int b = blockIdx.y, j = blockIdx.x, tid = threadIdx.x;
    const int a = aidx[0];

    __shared__ float sd[CIN * LROW];   // 16896 B

    float w[CIN * KW];
#pragma unroll
    for (int k = 0; k < CIN * KW; ++k) w[k] = W[a * CIN * KW + k];
    const float sb = bias[a];

    const float* dbase = data + (size_t)b * (CIN * (size_t)LEN);
    float* chrow = ch + (size_t)b * LCP;
    const int o0 = j * TILE;

    // ---- stage: wave w -> channel w, 260 float4s (1040 floats) per channel.
    // last block clamps to the true end of the channel row (248 float4s there,
    // which still covers every needed halo float exactly).
    {
        const int wv = tid >> 6, lane = tid & 63;
        const int nfl4 = min(260, (LEN - o0) >> 2);
        const float* gch = dbase + (size_t)wv * LEN + o0;
        float* lch = &sd[wv * LROW];
#pragma unroll
        for (int i = 0; i < 5; ++i) {
            const int idx = i * 64 + lane;
            if (idx < nfl4) g2l16(gch + 4 * idx, lch + i * 256);
        }
    }
    __syncthreads();   // drains vmcnt(0): all DMA landed

    // ---- compute from LDS: thread t -> outputs [o0+4t, o0+4t+4)
    const int o = o0 + 4 * tid;
    float aabs = 0.0f;

    float acc0 = sb, acc1 = sb, acc2 = sb, acc3 = sb;
#pragma unroll
    for (int c = 0; c < CIN; ++c) {
        const float4* xs = (const float4*)(sd + c * LROW + 4 * tid);
        const float4 v0 = xs[0], v1 = xs[1], v2 = xs[2], v3 = xs[3];
        float x[16] = { v0.x, v0.y, v0.z, v0.w,  v1.x, v1.y, v1.z, v1.w,
                        v2.x, v2.y, v2.z, v2.w,  v3.x, v3.y, v3.z, v3.w };
#pragma unroll
        for (int k = 0; k < KW; ++k) {
            const float wv = w[c * KW + k];
            acc0 = fmaf(x[k],     wv, acc0);
            acc1 = fmaf(x[k + 1], wv, acc1);
            acc2 = fmaf(x[k + 2], wv, acc2);
            acc3 = fmaf(x[k + 3], wv, acc3);
        }
    }
    const float y0 = leaky(acc0), y1 = leaky(acc1);
    const float y2 = leaky(acc2), y3 = leaky(acc3);

    if (o + EPT <= LC) {
        *(float4*)(chrow + o) = make_float4(y0, y1, y2, y3);
        aabs = (fabsf(y0) + fabsf(y1)) + (fabsf(y2) + fabsf(y3));
    } else if (o < LC) {               // last block partial thread
        const float yv[4] = { y0, y1, y2, y3 };
        for (int u = 0; u < LC - o; ++u) {
            chrow[o + u] = yv[u];
            aabs += fabsf(yv[u]);
        }
    }

#pragma unroll
    for (int off = 32; off; off >>= 1) aabs += __shfl_down(aabs, off);
    __shared__ float ra[4];
    if ((tid & 63) == 0) ra[tid >> 6] = aabs;
    __syncthreads();
    if (tid == 0)
        absP[b * NBX + j] = (double)((ra[0] + ra[1]) + (ra[2] + ra[3]));
}

// ---------------------------------------------------------------------------
// kernel 2: normalize + softmax-exp moments (no max shift: |c|<=1 after L1
// norm, exp(c) in [0.37, 2.72] — shift-invariance exact).  One float4/thread.
// ---------------------------------------------------------------------------
__global__ __launch_bounds__(256) void softmax_pass(
    const float* __restrict__ ch, const double* __restrict__ absP,
    float* __restrict__ chan_out, double* __restrict__ sP)
{
    const int b = blockIdx.y, j = blockIdx.x, tid = threadIdx.x;

    // redundant per-block row reduce of 293 partials (~1.2 KB, L2-served)
    __shared__ float sden;
    if (tid < 64) {
        double s = 0.0;
        for (int i = tid; i < NBX; i += 64) s += absP[b * NBX + i];
#pragma unroll
        for (int off = 32; off; off >>= 1) s += __shfl_down(s, off);
        if (tid == 0) sden = fmaxf((float)s, EPS_N);
    }
    __syncthreads();
    const float inv = 1.0f / sden;

    const float* src = ch + (size_t)b * LCP;
    float* dst = chan_out + (size_t)b * LC;   // elem base mod4 = (2b)&3
    const int o = j * (TPB * EPT) + tid * EPT;

    double te = 0.0, t1 = 0.0, t2 = 0.0;

    if (o + EPT <= LC) {
        const float4 v = *(const float4*)(src + o);
        const float c0 = v.x * inv, c1 = v.y * inv, c2 = v.z * inv, c3 = v.w * inv;
        if ((b & 1) == 0) {
            *(float4*)(dst + o) = make_float4(c0, c1, c2, c3);
        } else {                    // row base only 8B-aligned
            *(float2*)(dst + o)     = make_float2(c0, c1);
            *(float2*)(dst + o + 2) = make_float2(c2, c3);
        }
        const float e0 = expf(c0), e1 = expf(c1);
        const float e2 = expf(c2), e3 = expf(c3);
        const float se  = (e0 + e1) + (e2 + e3);
        const float su  = e1 + 2.0f * e2 + 3.0f * e3;
        const float suu = e1 + 4.0f * e2 + 9.0f * e3;
        const double od = (double)o;
        te = (double)se;
        t1 = od * (double)se + (double)su;
        t2 = od * od * (double)se + 2.0 * od * (double)su + (double)suu;
    } else {
        for (int l = o; l < LC; ++l) {
            const float c = src[l] * inv;
            dst[l] = c;
            const float e = expf(c);
            const double xd = (double)l;
            te += (double)e;
            t1 += (double)e * xd;
            t2 += (double)e * xd * xd;
        }
    }

#pragma unroll
    for (int off = 32; off; off >>= 1) {
        te += __shfl_down(te, off);
        t1 += __shfl_down(t1, off);
        t2 += __shfl_down(t2, off);
    }
    __shared__ double we[4], w1[4], w2[4];
    const int wv = tid >> 6;
    if ((tid & 63) == 0) { we[wv] = te; w1[wv] = t1; w2[wv] = t2; }
    __syncthreads();
    if (tid == 0) {
        double* p = sP + (size_t)(b * NBX + j) * 3;
        p[0] = (we[0] + we[1]) + (we[2] + we[3]);
        p[1] = (w1[0] + w1[1]) + (w1[2] + w1[3]);
        p[2] = (w2[0] + w2[1]) + (w2[2] + w2[3]);
    }
}

// ---------------------------------------------------------------------------
// kernel 3: finalize 16 rows
// ---------------------------------------------------------------------------
__global__ void finalize(const double* __restrict__ sP, float* __restrict__ out)
{
    const int b = blockIdx.x, t = threadIdx.x;
    double te = 0.0, t1 = 0.0, t2 = 0.0;
    for (int i = t; i < NBX; i += 64) {
        const double* p = sP + (size_t)(b * NBX + i) * 3;
        te += p[0]; t1 += p[1]; t2 += p[2];
    }
#pragma unroll
    for (int off = 32; off; off >>= 1) {
        te += __shfl_down(te, off);
        t1 += __shfl_down(t1, off);
        t2 += __shfl_down(t2, off);
    }
    if (t == 0) finalize_row(te, t1, t2, out, b);
}

extern "C" void kernel_launch(void* const* d_in, const int* in_sizes, int n_in,
                              void* d_out, int out_size, void* d_ws, size_t ws_size,
                              hipStream_t stream) {
    const float* data = (const float*)d_in[0];
    const float* W    = (const float*)d_in[1];
    const float* bias = (const float*)d_in[2];
    const int*   aidx = (const int*)d_in[3];
    float* out = (float*)d_out;

    char* ws = (char*)d_ws;
    double* absP = (double*)(ws + 0);
    double* sP   = (double*)(ws + 40960);
    float*  ch   = (float*) (ws + 196608);

    dim3 grid(NBX, BATCH);
    conv_stats<<<grid, dim3(TPB), 0, stream>>>(data, W, bias, aidx, ch, absP);
    softmax_pass<<<grid, dim3(TPB), 0, stream>>>(ch, absP, out + 2 * BATCH, sP);
    finalize<<<dim3(BATCH), dim3(64), 0, stream>>>(sP, out);
}